// Round 5
// baseline (359.785 us; speedup 1.0000x reference)
//
#include <hip/hip_runtime.h>

// PrecRec: confusion-matrix counts over 10 sigmoid thresholds.
//
// R5: async DMA staging. R1-R4 all pinned at ~3 TB/s because the compiler
// serializes VGPR-destined load batches (VGPR_Count never exceeded 60).
// global_load_lds consumes no VGPRs -> the load queue depth is structural,
// not allocator-dependent. Per-wave private double buffers in LDS, no
// __syncthreads in the main loop (no barrier drain).
// Bucketing via b = min(10, trunc(11*sigmoid(x))) (v_exp+v_rcp, ~14 VALU/elem);
// boundary-rounding diffs are ~1e2 elements vs 1.66e5 tolerance.

#define NTHR 10
#define NBKT 11            // bucket = #thresholds passed, 0..10
#define NCNT 22            // ws: [0..10]=P-bucket counts, [11..21]=TP-bucket
#define WS_STRIDE 16       // 64 B between counters

typedef unsigned long long u64;
typedef unsigned u32;

typedef __attribute__((address_space(3))) void* lds_vp;
typedef const __attribute__((address_space(1))) void* gbl_vp;

__device__ __forceinline__ void ld_lds16(const void* g, void* l) {
    // one wave-instruction: 64 lanes x 16 B -> lds_base + lane*16
    __builtin_amdgcn_global_load_lds((gbl_vp)g, (lds_vp)l, 16, 0, 0);
}

__device__ __forceinline__ unsigned wave_reduce_add(unsigned v) {
#pragma unroll
    for (int off = 32; off > 0; off >>= 1)
        v += __shfl_down(v, off, 64);
    return v;
}

__global__ __launch_bounds__(64) void zero_ws_kernel(u32* __restrict__ ws) {
    int i = threadIdx.x;
    if (i < NCNT) ws[i * WS_STRIDE] = 0u;
}

__device__ __forceinline__ void acc_elem(float x, u32 mm, u32 tt, u64& hP, u64& hT) {
    u32 mt = mm & tt;
    // bucket = #(sigmoid(x) > j/11, j=1..10) = min(10, floor(11*sigmoid(x)))
    float e = __expf(-x);                          // v_mul + v_exp
    float s = __builtin_amdgcn_rcpf(1.0f + e);     // v_add + v_rcp
    int bi = (int)(s * 11.0f);                     // v_mul + v_cvt (s>=0: trunc==floor)
    u32 b = (u32)(bi > 10 ? 10 : bi);              // guard s==1.0
    u32 sh = b * 5u;
    hP += (u64)mm << sh;
    hT += (u64)mt << sh;
}

__device__ __forceinline__ void acc_vec(const float4& p, const int4& m, const int4& t,
                                        u64& hP, u64& hT) {
    acc_elem(p.x, (u32)m.x, (u32)t.x, hP, hT);
    acc_elem(p.y, (u32)m.y, (u32)t.y, hP, hT);
    acc_elem(p.z, (u32)m.z, (u32)t.z, hP, hT);
    acc_elem(p.w, (u32)m.w, (u32)t.w, hP, hT);
}

__device__ __forceinline__ void flush_hist(u64& hP, u64& hT,
                                           u64& Plo, u64& Phi, u64& Tlo, u64& Thi) {
#pragma unroll
    for (int b = 0; b < 6; ++b) {
        Plo += (u64)((u32)(hP >> (5 * b)) & 31u) << (10 * b);
        Tlo += (u64)((u32)(hT >> (5 * b)) & 31u) << (10 * b);
    }
#pragma unroll
    for (int b = 6; b < NBKT; ++b) {
        Phi += (u64)((u32)(hP >> (5 * b)) & 31u) << (10 * (b - 6));
        Thi += (u64)((u32)(hT >> (5 * b)) & 31u) << (10 * (b - 6));
    }
    hP = 0ull; hT = 0ull;
}

// chunk = 64 float4-groups per array = 256 elems; 1 KB per array per chunk.
__global__ __launch_bounds__(256) void count_kernel(
        const float4* __restrict__ pred4,
        const int4*  __restrict__ mask4,
        const int4*  __restrict__ targ4,
        const float* __restrict__ pred,
        const int*   __restrict__ mask,
        const int*   __restrict__ targ,
        u32* __restrict__ ws, int nvec, int n) {
    // per-wave double-buffered staging: [wave][buf][array][64 lanes * 16 B]
    __shared__ __align__(16) unsigned char stage[4][2][3][1024];
    __shared__ u32 partial[4][NCNT];

    u64 Plo = 0ull, Phi = 0ull, Tlo = 0ull, Thi = 0ull;

    const int tid        = blockIdx.x * blockDim.x + threadIdx.x;
    const int lane       = threadIdx.x & 63;
    const int wv         = threadIdx.x >> 6;
    const int waveG      = tid >> 6;
    const int totalWaves = (gridDim.x * blockDim.x) >> 6;
    const int nchunks    = nvec >> 6;   // full 64-group chunks

    // NOTE: per-thread elems = 4 * ceil(nchunks/totalWaves); must stay <=1023
    // for the 10-bit level-2 fields. Here: 4*16 = 64.

    int c   = waveG;
    int buf = 0;
    if (c < nchunks) {
        int gb = c << 6;
        ld_lds16(pred4 + gb + lane, stage[wv][0][0]);
        ld_lds16(mask4 + gb + lane, stage[wv][0][1]);
        ld_lds16(targ4 + gb + lane, stage[wv][0][2]);
    }
    while (c < nchunks) {
        int cn = c + totalWaves;
        if (cn < nchunks) {
            int gb = cn << 6;
            ld_lds16(pred4 + gb + lane, stage[wv][buf ^ 1][0]);
            ld_lds16(mask4 + gb + lane, stage[wv][buf ^ 1][1]);
            ld_lds16(targ4 + gb + lane, stage[wv][buf ^ 1][2]);
        }
        // compiler inserts the vmcnt wait for THIS buffer's DMA before ds_read
        const float4* lp = (const float4*)stage[wv][buf][0];
        const int4*   lm = (const int4*)  stage[wv][buf][1];
        const int4*   lt = (const int4*)  stage[wv][buf][2];
        float4 p = lp[lane];
        int4   m = lm[lane];
        int4   t = lt[lane];

        u64 hP = 0ull, hT = 0ull;
        acc_vec(p, m, t, hP, hT);                  // 4 elems: max field = 4 < 31
        flush_hist(hP, hT, Plo, Phi, Tlo, Thi);

        c = cn;
        buf ^= 1;
    }

    // generic tails (empty for 32x1024x1024, kept for safety)
    for (int g = (nchunks << 6) + tid; g < nvec; g += gridDim.x * blockDim.x) {
        u64 hP = 0ull, hT = 0ull;
        acc_vec(pred4[g], mask4[g], targ4[g], hP, hT);
        flush_hist(hP, hT, Plo, Phi, Tlo, Thi);
    }
    {
        int i = nvec * 4 + tid;
        if (i < n) {
            u64 hP = 0ull, hT = 0ull;
            acc_elem(pred[i], (u32)mask[i], (u32)targ[i], hP, hT);
            flush_hist(hP, hT, Plo, Phi, Tlo, Thi);
        }
    }

    // unpack level-2 (10-bit fields)
    u32 vals[NCNT];
#pragma unroll
    for (int b = 0; b < 6; ++b) {
        vals[b]        = (u32)(Plo >> (10 * b)) & 1023u;
        vals[NBKT + b] = (u32)(Tlo >> (10 * b)) & 1023u;
    }
#pragma unroll
    for (int b = 6; b < NBKT; ++b) {
        vals[b]        = (u32)(Phi >> (10 * (b - 6))) & 1023u;
        vals[NBKT + b] = (u32)(Thi >> (10 * (b - 6))) & 1023u;
    }
#pragma unroll
    for (int cc = 0; cc < NCNT; ++cc) vals[cc] = wave_reduce_add(vals[cc]);

    if (lane == 0) {
#pragma unroll
        for (int cc = 0; cc < NCNT; ++cc) partial[wv][cc] = vals[cc];
    }
    __syncthreads();
    if (threadIdx.x < NCNT) {
        u32 s = partial[0][threadIdx.x] + partial[1][threadIdx.x] +
                partial[2][threadIdx.x] + partial[3][threadIdx.x];
        atomicAdd(&ws[threadIdx.x * WS_STRIDE], s);
    }
}

__global__ __launch_bounds__(64) void finalize_kernel(const u32* __restrict__ ws,
                                                      float* __restrict__ out) {
    int j = threadIdx.x;
    if (j < NTHR) {
        u32 totM = 0u, totT = 0u, p = 0u, tp = 0u;
#pragma unroll
        for (int b = 0; b < NBKT; ++b) {
            u32 vP = ws[b * WS_STRIDE];
            u32 vT = ws[(NBKT + b) * WS_STRIDE];
            totM += vP; totT += vT;
            if (b > j) { p += vP; tp += vT; }
        }
        u32 fp = p - tp;
        u32 fn = totT - tp;
        u32 tn = totM - p - fn;
        out[j]            = (float)tp;
        out[NTHR + j]     = (float)fp;
        out[2 * NTHR + j] = (float)tn;
        out[3 * NTHR + j] = (float)fn;
    }
}

extern "C" void kernel_launch(void* const* d_in, const int* in_sizes, int n_in,
                              void* d_out, int out_size, void* d_ws, size_t ws_size,
                              hipStream_t stream) {
    const float* pred = (const float*)d_in[0];
    const int*   mask = (const int*)d_in[1];
    const int*   targ = (const int*)d_in[2];
    u32*         ws   = (u32*)d_ws;
    float*       out  = (float*)d_out;

    const int n    = in_sizes[0];
    const int nvec = n / 4;

    zero_ws_kernel<<<1, 64, 0, stream>>>(ws);

    // 2048 blocks x 4 waves = 8192 waves; nchunks = 131072 -> 16 chunks/wave.
    // LDS 24.3 KB/block -> 6 blocks/CU resident (24 waves/CU).
    const int blocks = 2048;
    count_kernel<<<blocks, 256, 0, stream>>>(
        (const float4*)pred, (const int4*)mask, (const int4*)targ,
        pred, mask, targ, ws, nvec, n);

    finalize_kernel<<<1, 64, 0, stream>>>(ws, out);
}

// Round 6
// 353.080 us; speedup vs baseline: 1.0190x; 1.0190x over previous
//
#include <hip/hip_runtime.h>

// PrecRec: confusion-matrix counts over 10 sigmoid thresholds.
//
// R6 (final consolidation): five structurally different kernels (R1-R5) all
// pin at 2.8-3.1 TB/s effective read rate with no pipe >27% busy and
// L3-served replays running at identical speed -> shared read-path
// concurrency ceiling. The docs' "6.3 TB/s achievable" (m13) is a COPY =
// 3.15 TB/s read + 3.15 TB/s write; no measured datapoint on this chip
// exceeds ~3.3 TB/s pure-read. 402 MB / 3.15 TB/s = ~128 us floor; R4's best
// dispatch hit 130.2 us (97%).
//
// Structure: R3's wave-chunked batch-4 (best measured: 130-135 us), with
// R5's cheap sigmoid bucketing (absmax 0.0 verified in R5; ~8 VALU/elem):
//   bucket = min(10, trunc(11*sigmoid(x))), sigmoid via v_exp + v_rcp.
// Packed u64 histograms: level-1 5-bit x 11 (<=16 elems/iter, cap 31),
// level-2 10-bit x 11 (<=64 elems/thread, cap 1023). p/tp = suffix sums.

#define NTHR 10
#define NBKT 11            // bucket = #thresholds passed, 0..10
#define NCNT 22            // ws: [0..10]=P-bucket counts, [11..21]=TP-bucket
#define WS_STRIDE 16       // 64 B between counters

typedef unsigned long long u64;
typedef unsigned u32;

__device__ __forceinline__ unsigned wave_reduce_add(unsigned v) {
#pragma unroll
    for (int off = 32; off > 0; off >>= 1)
        v += __shfl_down(v, off, 64);
    return v;
}

__global__ __launch_bounds__(64) void zero_ws_kernel(u32* __restrict__ ws) {
    int i = threadIdx.x;
    if (i < NCNT) ws[i * WS_STRIDE] = 0u;
}

__device__ __forceinline__ void acc_elem(float x, u32 mm, u32 tt, u64& hP, u64& hT) {
    u32 mt = mm & tt;
    // bucket = #(sigmoid(x) > j/11) = min(10, floor(11*sigmoid(x)))
    float e = __expf(-x);                          // v_mul + v_exp
    float s = __builtin_amdgcn_rcpf(1.0f + e);     // v_add + v_rcp
    int bi = (int)(s * 11.0f);                     // v_mul + v_cvt (s>=0)
    u32 b = (u32)(bi > 10 ? 10 : bi);              // guard s==1.0
    u32 sh = b * 5u;
    hP += (u64)mm << sh;
    hT += (u64)mt << sh;
}

__device__ __forceinline__ void acc_vec(const float4& p, const int4& m, const int4& t,
                                        u64& hP, u64& hT) {
    acc_elem(p.x, (u32)m.x, (u32)t.x, hP, hT);
    acc_elem(p.y, (u32)m.y, (u32)t.y, hP, hT);
    acc_elem(p.z, (u32)m.z, (u32)t.z, hP, hT);
    acc_elem(p.w, (u32)m.w, (u32)t.w, hP, hT);
}

__device__ __forceinline__ void flush_hist(u64& hP, u64& hT,
                                           u64& Plo, u64& Phi, u64& Tlo, u64& Thi) {
#pragma unroll
    for (int b = 0; b < 6; ++b) {
        Plo += (u64)((u32)(hP >> (5 * b)) & 31u) << (10 * b);
        Tlo += (u64)((u32)(hT >> (5 * b)) & 31u) << (10 * b);
    }
#pragma unroll
    for (int b = 6; b < NBKT; ++b) {
        Phi += (u64)((u32)(hP >> (5 * b)) & 31u) << (10 * (b - 6));
        Thi += (u64)((u32)(hT >> (5 * b)) & 31u) << (10 * (b - 6));
    }
    hP = 0ull; hT = 0ull;
}

__global__ __launch_bounds__(256) void count_kernel(
        const float4* __restrict__ pred4,
        const int4*  __restrict__ mask4,
        const int4*  __restrict__ targ4,
        const float* __restrict__ pred,
        const int*   __restrict__ mask,
        const int*   __restrict__ targ,
        u32* __restrict__ ws, int nvec, int n) {
    u64 Plo = 0ull, Phi = 0ull, Tlo = 0ull, Thi = 0ull;

    const int tid    = blockIdx.x * blockDim.x + threadIdx.x;
    const int lane   = tid & 63;
    const int waveId = tid >> 6;
    const int totalWaves = (gridDim.x * blockDim.x) >> 6;
    const int strideG    = totalWaves << 8;     // waves * 256 groups/iter

    for (int base = waveId << 8; base < nvec; base += strideG) {
        u64 hP = 0ull, hT = 0ull;
        if (base + 256 <= nvec) {
            // 12 independent 16B loads, issued before any use
            float4 p0 = pred4[base +        lane];
            float4 p1 = pred4[base +  64  + lane];
            float4 p2 = pred4[base + 128  + lane];
            float4 p3 = pred4[base + 192  + lane];
            int4   m0 = mask4[base +        lane];
            int4   m1 = mask4[base +  64  + lane];
            int4   m2 = mask4[base + 128  + lane];
            int4   m3 = mask4[base + 192  + lane];
            int4   t0 = targ4[base +        lane];
            int4   t1 = targ4[base +  64  + lane];
            int4   t2 = targ4[base + 128  + lane];
            int4   t3 = targ4[base + 192  + lane];
            acc_vec(p0, m0, t0, hP, hT);
            acc_vec(p1, m1, t1, hP, hT);
            acc_vec(p2, m2, t2, hP, hT);
            acc_vec(p3, m3, t3, hP, hT);
        } else {
#pragma unroll
            for (int c = 0; c < 4; ++c) {
                int g = base + (c << 6) + lane;
                if (g < nvec)
                    acc_vec(pred4[g], mask4[g], targ4[g], hP, hT);
            }
        }
        flush_hist(hP, hT, Plo, Phi, Tlo, Thi);   // <=16 elems per 5-bit field
    }

    // scalar tail (n % 4)
    {
        int i = nvec * 4 + tid;
        if (i < n) {
            u64 hP = 0ull, hT = 0ull;
            acc_elem(pred[i], (u32)mask[i], (u32)targ[i], hP, hT);
            flush_hist(hP, hT, Plo, Phi, Tlo, Thi);
        }
    }

    // unpack level-2 (10-bit fields; per-thread elems <= 64 << 1023 cap)
    u32 vals[NCNT];
#pragma unroll
    for (int b = 0; b < 6; ++b) {
        vals[b]        = (u32)(Plo >> (10 * b)) & 1023u;
        vals[NBKT + b] = (u32)(Tlo >> (10 * b)) & 1023u;
    }
#pragma unroll
    for (int b = 6; b < NBKT; ++b) {
        vals[b]        = (u32)(Phi >> (10 * (b - 6))) & 1023u;
        vals[NBKT + b] = (u32)(Thi >> (10 * (b - 6))) & 1023u;
    }
#pragma unroll
    for (int c = 0; c < NCNT; ++c) vals[c] = wave_reduce_add(vals[c]);

    __shared__ u32 partial[4][NCNT];
    const int wave = threadIdx.x >> 6;
    if ((threadIdx.x & 63) == 0) {
#pragma unroll
        for (int c = 0; c < NCNT; ++c) partial[wave][c] = vals[c];
    }
    __syncthreads();
    if (threadIdx.x < NCNT) {
        u32 s = partial[0][threadIdx.x] + partial[1][threadIdx.x] +
                partial[2][threadIdx.x] + partial[3][threadIdx.x];
        atomicAdd(&ws[threadIdx.x * WS_STRIDE], s);
    }
}

__global__ __launch_bounds__(64) void finalize_kernel(const u32* __restrict__ ws,
                                                      float* __restrict__ out) {
    int j = threadIdx.x;
    if (j < NTHR) {
        u32 totM = 0u, totT = 0u, p = 0u, tp = 0u;
#pragma unroll
        for (int b = 0; b < NBKT; ++b) {
            u32 vP = ws[b * WS_STRIDE];
            u32 vT = ws[(NBKT + b) * WS_STRIDE];
            totM += vP; totT += vT;
            if (b > j) { p += vP; tp += vT; }
        }
        u32 fp = p - tp;
        u32 fn = totT - tp;
        u32 tn = totM - p - fn;
        out[j]            = (float)tp;
        out[NTHR + j]     = (float)fp;
        out[2 * NTHR + j] = (float)tn;
        out[3 * NTHR + j] = (float)fn;
    }
}

extern "C" void kernel_launch(void* const* d_in, const int* in_sizes, int n_in,
                              void* d_out, int out_size, void* d_ws, size_t ws_size,
                              hipStream_t stream) {
    const float* pred = (const float*)d_in[0];
    const int*   mask = (const int*)d_in[1];
    const int*   targ = (const int*)d_in[2];
    u32*         ws   = (u32*)d_ws;
    float*       out  = (float*)d_out;

    const int n    = in_sizes[0];
    const int nvec = n / 4;

    zero_ws_kernel<<<1, 64, 0, stream>>>(ws);

    // 2048 blocks x 256 = 8192 waves; 4 iterations/wave at this size.
    const int blocks = 2048;
    count_kernel<<<blocks, 256, 0, stream>>>(
        (const float4*)pred, (const int4*)mask, (const int4*)targ,
        pred, mask, targ, ws, nvec, n);

    finalize_kernel<<<1, 64, 0, stream>>>(ws, out);
}